// Round 1
// baseline (15922.794 us; speedup 1.0000x reference)
//
#include <hip/hip_runtime.h>
#include <math.h>

#define BB 512
#define TT 2048
#define HH 64
#define G4 256   // 4*H

__device__ __forceinline__ float sigmoid_fast(float x) {
    float e = __expf(-x);                       // v_mul + v_exp_f32
    return __builtin_amdgcn_rcpf(1.0f + e);     // v_rcp_f32, ~1 ulp
}
__device__ __forceinline__ float tanh_fast(float x) {
    // tanh(x) = 2/(1+exp(-2x)) - 1
    float e = __expf(-2.0f * x);
    return fmaf(2.0f, __builtin_amdgcn_rcpf(1.0f + e), -1.0f);
}

__global__ __launch_bounds__(256, 2)
void lstm_fused_kernel(const float* __restrict__ x,      // [B,T]
                       const float* __restrict__ w_ih0,  // [256,1]
                       const float* __restrict__ w_hh0,  // [256,64]
                       const float* __restrict__ b_ih0,  // [256]
                       const float* __restrict__ b_hh0,  // [256]
                       const float* __restrict__ w_ih1,  // [256,64]
                       const float* __restrict__ w_hh1,  // [256,64]
                       const float* __restrict__ b_ih1,  // [256]
                       const float* __restrict__ b_hh1,  // [256]
                       const float* __restrict__ w1, const float* __restrict__ b1,  // [64,64],[64]
                       const float* __restrict__ w2, const float* __restrict__ b2,  // [32,64],[32]
                       const float* __restrict__ w3, const float* __restrict__ b3,  // [10,32],[10]
                       float* __restrict__ out)          // [B,10]
{
    const int b = blockIdx.x;
    const int r = threadIdx.x;      // gate row 0..255
    const int wv = r >> 6;          // wave id == gate id: 0=i 1=f 2=g 3=o

    __shared__ float xs[TT];        // 8 KB staged input sequence
    __shared__ float h0s[HH];
    __shared__ float h1s[HH];
    __shared__ float acts[G4];
    __shared__ float cls[HH + 32];

    // ---- stage x[b][*] into LDS (coalesced float4) ----
    {
        const float4* xg = (const float4*)(x + (size_t)b * TT);
        float4* xl = (float4*)xs;
        #pragma unroll
        for (int i = 0; i < TT / 4 / 256; ++i) xl[r + 256 * i] = xg[r + 256 * i];
    }

    // ---- per-thread weight rows into registers (3 x 64 = 192 VGPRs) ----
    float w0r[HH], wAr[HH], wBr[HH];
    {
        const float4* p0 = (const float4*)(w_hh0 + r * HH);
        const float4* pa = (const float4*)(w_ih1 + r * HH);
        const float4* pb = (const float4*)(w_hh1 + r * HH);
        #pragma unroll
        for (int k = 0; k < HH / 4; ++k) {
            float4 v = p0[k];
            w0r[4*k+0] = v.x; w0r[4*k+1] = v.y; w0r[4*k+2] = v.z; w0r[4*k+3] = v.w;
        }
        #pragma unroll
        for (int k = 0; k < HH / 4; ++k) {
            float4 v = pa[k];
            wAr[4*k+0] = v.x; wAr[4*k+1] = v.y; wAr[4*k+2] = v.z; wAr[4*k+3] = v.w;
        }
        #pragma unroll
        for (int k = 0; k < HH / 4; ++k) {
            float4 v = pb[k];
            wBr[4*k+0] = v.x; wBr[4*k+1] = v.y; wBr[4*k+2] = v.z; wBr[4*k+3] = v.w;
        }
    }
    const float bias0 = b_ih0[r] + b_hh0[r];
    const float bias1 = b_ih1[r] + b_hh1[r];
    const float wih0r = w_ih0[r];

    if (r < HH) { h0s[r] = 0.0f; h1s[r] = 0.0f; }
    float c0 = 0.0f, c1 = 0.0f;   // cell states, owned by wave 0 (r < 64)
    __syncthreads();

    for (int t = 0; t < TT; ++t) {
        // ---- layer-0 gates: bias + w_ih0*x_t + Whh0 . h0_old ----
        float acc0 = fmaf(wih0r, xs[t], bias0);
        #pragma unroll
        for (int k = 0; k < HH; k += 4) {
            float4 h4 = *(const float4*)&h0s[k];   // broadcast ds_read_b128
            acc0 = fmaf(w0r[k+0], h4.x, acc0);
            acc0 = fmaf(w0r[k+1], h4.y, acc0);
            acc0 = fmaf(w0r[k+2], h4.z, acc0);
            acc0 = fmaf(w0r[k+3], h4.w, acc0);
        }
        // ---- layer-1 partial: bias + Whh1 . h1_old (independent of h0 update) ----
        float acc1 = bias1;
        #pragma unroll
        for (int k = 0; k < HH; k += 4) {
            float4 h4 = *(const float4*)&h1s[k];
            acc1 = fmaf(wBr[k+0], h4.x, acc1);
            acc1 = fmaf(wBr[k+1], h4.y, acc1);
            acc1 = fmaf(wBr[k+2], h4.z, acc1);
            acc1 = fmaf(wBr[k+3], h4.w, acc1);
        }
        float a0 = (wv == 2) ? tanh_fast(acc0) : sigmoid_fast(acc0);
        acts[r] = a0;
        __syncthreads();

        if (r < HH) {   // wave 0 combines gates, updates c0/h0
            float gi = acts[r], gf = acts[64 + r], gg = acts[128 + r], go = acts[192 + r];
            c0 = fmaf(gf, c0, gi * gg);
            h0s[r] = go * tanh_fast(c0);
        }
        __syncthreads();

        // ---- layer-1 remaining: Wih1 . h0_new ----
        #pragma unroll
        for (int k = 0; k < HH; k += 4) {
            float4 h4 = *(const float4*)&h0s[k];
            acc1 = fmaf(wAr[k+0], h4.x, acc1);
            acc1 = fmaf(wAr[k+1], h4.y, acc1);
            acc1 = fmaf(wAr[k+2], h4.z, acc1);
            acc1 = fmaf(wAr[k+3], h4.w, acc1);
        }
        float a1 = (wv == 2) ? tanh_fast(acc1) : sigmoid_fast(acc1);
        acts[r] = a1;
        __syncthreads();

        if (r < HH) {   // wave 0 combines gates, updates c1/h1
            float gi = acts[r], gf = acts[64 + r], gg = acts[128 + r], go = acts[192 + r];
            c1 = fmaf(gf, c1, gi * gg);
            h1s[r] = go * tanh_fast(c1);
        }
        __syncthreads();
    }

    // ---- classifier head on h1s (h_last) ----
    if (r < 64) {
        float a = b1[r];
        #pragma unroll 8
        for (int k = 0; k < 64; ++k) a = fmaf(w1[r * 64 + k], h1s[k], a);
        cls[r] = fmaxf(a, 0.0f);
    }
    __syncthreads();
    if (r < 32) {
        float a = b2[r];
        #pragma unroll 8
        for (int k = 0; k < 64; ++k) a = fmaf(w2[r * 64 + k], cls[k], a);
        cls[64 + r] = fmaxf(a, 0.0f);
    }
    __syncthreads();
    if (r < 10) {
        float a = b3[r];
        #pragma unroll 8
        for (int k = 0; k < 32; ++k) a = fmaf(w3[r * 32 + k], cls[64 + k], a);
        out[b * 10 + r] = a;
    }
}

extern "C" void kernel_launch(void* const* d_in, const int* in_sizes, int n_in,
                              void* d_out, int out_size, void* d_ws, size_t ws_size,
                              hipStream_t stream) {
    const float* x     = (const float*)d_in[0];
    const float* w_ih0 = (const float*)d_in[1];
    const float* w_hh0 = (const float*)d_in[2];
    const float* b_ih0 = (const float*)d_in[3];
    const float* b_hh0 = (const float*)d_in[4];
    const float* w_ih1 = (const float*)d_in[5];
    const float* w_hh1 = (const float*)d_in[6];
    const float* b_ih1 = (const float*)d_in[7];
    const float* b_hh1 = (const float*)d_in[8];
    const float* w1    = (const float*)d_in[9];
    const float* b1    = (const float*)d_in[10];
    const float* w2    = (const float*)d_in[11];
    const float* b2    = (const float*)d_in[12];
    const float* w3    = (const float*)d_in[13];
    const float* b3    = (const float*)d_in[14];
    float* out = (float*)d_out;

    lstm_fused_kernel<<<BB, 256, 0, stream>>>(x, w_ih0, w_hh0, b_ih0, b_hh0,
                                              w_ih1, w_hh1, b_ih1, b_hh1,
                                              w1, b1, w2, b2, w3, b3, out);
}

// Round 2
// 14958.519 us; speedup vs baseline: 1.0645x; 1.0645x over previous
//
#include <hip/hip_runtime.h>
#include <math.h>

#define BB 512
#define TT 2048
#define HH 64
#define G4 256   // 4*H

__device__ __forceinline__ float sigmoid_fast(float x) {
    float e = __expf(-x);                       // v_mul + v_exp_f32
    return __builtin_amdgcn_rcpf(1.0f + e);     // v_rcp_f32, ~1 ulp
}
__device__ __forceinline__ float tanh_fast(float x) {
    // tanh(x) = 2/(1+exp(-2x)) - 1
    float e = __expf(-2.0f * x);
    return fmaf(2.0f, __builtin_amdgcn_rcpf(1.0f + e), -1.0f);
}

__global__ __launch_bounds__(256, 2)
void lstm_fused_kernel(const float* __restrict__ x,      // [B,T]
                       const float* __restrict__ w_ih0,  // [256,1]
                       const float* __restrict__ w_hh0,  // [256,64]
                       const float* __restrict__ b_ih0,  // [256]
                       const float* __restrict__ b_hh0,  // [256]
                       const float* __restrict__ w_ih1,  // [256,64]
                       const float* __restrict__ w_hh1,  // [256,64]
                       const float* __restrict__ b_ih1,  // [256]
                       const float* __restrict__ b_hh1,  // [256]
                       const float* __restrict__ w1, const float* __restrict__ b1,  // [64,64],[64]
                       const float* __restrict__ w2, const float* __restrict__ b2,  // [32,64],[32]
                       const float* __restrict__ w3, const float* __restrict__ b3,  // [10,32],[10]
                       float* __restrict__ out)          // [B,10]
{
    const int b = blockIdx.x;
    const int r = threadIdx.x;      // gate row 0..255
    const int wv = r >> 6;          // wave id == gate id: 0=i 1=f 2=g 3=o

    __shared__ float xs[TT];        // 8 KB staged input sequence
    __shared__ float h0s[HH];
    __shared__ float h1s[HH];
    __shared__ float acts[G4];
    __shared__ float cls[HH + 32];

    // ---- stage x[b][*] into LDS (coalesced float4) ----
    {
        const float4* xg = (const float4*)(x + (size_t)b * TT);
        float4* xl = (float4*)xs;
        #pragma unroll
        for (int i = 0; i < TT / 4 / 256; ++i) xl[r + 256 * i] = xg[r + 256 * i];
    }

    // ---- per-thread weight rows into registers (3 x 64 = 192 VGPRs) ----
    float w0r[HH], wAr[HH], wBr[HH];
    {
        const float4* p0 = (const float4*)(w_hh0 + r * HH);
        const float4* pa = (const float4*)(w_ih1 + r * HH);
        const float4* pb = (const float4*)(w_hh1 + r * HH);
        #pragma unroll
        for (int k = 0; k < HH / 4; ++k) {
            float4 v = p0[k];
            w0r[4*k+0] = v.x; w0r[4*k+1] = v.y; w0r[4*k+2] = v.z; w0r[4*k+3] = v.w;
        }
        #pragma unroll
        for (int k = 0; k < HH / 4; ++k) {
            float4 v = pa[k];
            wAr[4*k+0] = v.x; wAr[4*k+1] = v.y; wAr[4*k+2] = v.z; wAr[4*k+3] = v.w;
        }
        #pragma unroll
        for (int k = 0; k < HH / 4; ++k) {
            float4 v = pb[k];
            wBr[4*k+0] = v.x; wBr[4*k+1] = v.y; wBr[4*k+2] = v.z; wBr[4*k+3] = v.w;
        }
    }

    // ---- PIN the weights in VGPRs: make each value opaque so the compiler
    // cannot rematerialize the global loads inside the timestep loop.
    // (Round-1 failure mode: VGPR_Count=128, 41 GB HBM reload traffic.)
    #pragma unroll
    for (int k = 0; k < HH; ++k) {
        asm volatile("" : "+v"(w0r[k]));
        asm volatile("" : "+v"(wAr[k]));
        asm volatile("" : "+v"(wBr[k]));
    }

    const float bias0 = b_ih0[r] + b_hh0[r];
    const float bias1 = b_ih1[r] + b_hh1[r];
    const float wih0r = w_ih0[r];

    if (r < HH) { h0s[r] = 0.0f; h1s[r] = 0.0f; }
    float c0 = 0.0f, c1 = 0.0f;   // cell states, owned by wave 0 (r < 64)
    __syncthreads();

    for (int t = 0; t < TT; ++t) {
        // ---- layer-0 gates: bias + w_ih0*x_t + Whh0 . h0_old ----
        float acc0 = fmaf(wih0r, xs[t], bias0);
        #pragma unroll
        for (int k = 0; k < HH; k += 4) {
            float4 h4 = *(const float4*)&h0s[k];   // broadcast ds_read_b128
            acc0 = fmaf(w0r[k+0], h4.x, acc0);
            acc0 = fmaf(w0r[k+1], h4.y, acc0);
            acc0 = fmaf(w0r[k+2], h4.z, acc0);
            acc0 = fmaf(w0r[k+3], h4.w, acc0);
        }
        // ---- layer-1 partial: bias + Whh1 . h1_old (independent of h0 update) ----
        float acc1 = bias1;
        #pragma unroll
        for (int k = 0; k < HH; k += 4) {
            float4 h4 = *(const float4*)&h1s[k];
            acc1 = fmaf(wBr[k+0], h4.x, acc1);
            acc1 = fmaf(wBr[k+1], h4.y, acc1);
            acc1 = fmaf(wBr[k+2], h4.z, acc1);
            acc1 = fmaf(wBr[k+3], h4.w, acc1);
        }
        float a0 = (wv == 2) ? tanh_fast(acc0) : sigmoid_fast(acc0);
        acts[r] = a0;
        __syncthreads();

        if (r < HH) {   // wave 0 combines gates, updates c0/h0
            float gi = acts[r], gf = acts[64 + r], gg = acts[128 + r], go = acts[192 + r];
            c0 = fmaf(gf, c0, gi * gg);
            h0s[r] = go * tanh_fast(c0);
        }
        __syncthreads();

        // ---- layer-1 remaining: Wih1 . h0_new ----
        #pragma unroll
        for (int k = 0; k < HH; k += 4) {
            float4 h4 = *(const float4*)&h0s[k];
            acc1 = fmaf(wAr[k+0], h4.x, acc1);
            acc1 = fmaf(wAr[k+1], h4.y, acc1);
            acc1 = fmaf(wAr[k+2], h4.z, acc1);
            acc1 = fmaf(wAr[k+3], h4.w, acc1);
        }
        float a1 = (wv == 2) ? tanh_fast(acc1) : sigmoid_fast(acc1);
        acts[r] = a1;
        __syncthreads();

        if (r < HH) {   // wave 0 combines gates, updates c1/h1
            float gi = acts[r], gf = acts[64 + r], gg = acts[128 + r], go = acts[192 + r];
            c1 = fmaf(gf, c1, gi * gg);
            h1s[r] = go * tanh_fast(c1);
        }
        __syncthreads();
    }

    // ---- classifier head on h1s (h_last) ----
    if (r < 64) {
        float a = b1[r];
        #pragma unroll 8
        for (int k = 0; k < 64; ++k) a = fmaf(w1[r * 64 + k], h1s[k], a);
        cls[r] = fmaxf(a, 0.0f);
    }
    __syncthreads();
    if (r < 32) {
        float a = b2[r];
        #pragma unroll 8
        for (int k = 0; k < 64; ++k) a = fmaf(w2[r * 64 + k], cls[k], a);
        cls[64 + r] = fmaxf(a, 0.0f);
    }
    __syncthreads();
    if (r < 10) {
        float a = b3[r];
        #pragma unroll 8
        for (int k = 0; k < 32; ++k) a = fmaf(w3[r * 32 + k], cls[64 + k], a);
        out[b * 10 + r] = a;
    }
}

extern "C" void kernel_launch(void* const* d_in, const int* in_sizes, int n_in,
                              void* d_out, int out_size, void* d_ws, size_t ws_size,
                              hipStream_t stream) {
    const float* x     = (const float*)d_in[0];
    const float* w_ih0 = (const float*)d_in[1];
    const float* w_hh0 = (const float*)d_in[2];
    const float* b_ih0 = (const float*)d_in[3];
    const float* b_hh0 = (const float*)d_in[4];
    const float* w_ih1 = (const float*)d_in[5];
    const float* w_hh1 = (const float*)d_in[6];
    const float* b_ih1 = (const float*)d_in[7];
    const float* b_hh1 = (const float*)d_in[8];
    const float* w1    = (const float*)d_in[9];
    const float* b1    = (const float*)d_in[10];
    const float* w2    = (const float*)d_in[11];
    const float* b2    = (const float*)d_in[12];
    const float* w3    = (const float*)d_in[13];
    const float* b3    = (const float*)d_in[14];
    float* out = (float*)d_out;

    lstm_fused_kernel<<<BB, 256, 0, stream>>>(x, w_ih0, w_hh0, b_ih0, b_hh0,
                                              w_ih1, w_hh1, b_ih1, b_hh1,
                                              w1, b1, w2, b2, w3, b3, out);
}

// Round 3
// 4093.121 us; speedup vs baseline: 3.8901x; 3.6546x over previous
//
#include <hip/hip_runtime.h>
#include <math.h>

#define BB 512
#define TT 2048
#define HH 64

__device__ __forceinline__ float sigmoid_fast(float x) {
    float e = __expf(-x);
    return __builtin_amdgcn_rcpf(1.0f + e);
}
__device__ __forceinline__ float tanh_fast(float x) {
    float e = __expf(-2.0f * x);
    return fmaf(2.0f, __builtin_amdgcn_rcpf(1.0f + e), -1.0f);
}

// 1024 threads = 16 waves. wave w owns gate rows [16w, 16w+16); lane quarter
// q owns K-slice [16q, 16q+16). 48 weight floats/thread -> ~90 VGPR, no spill.
// Cell state c0/c1 is replicated per wave (lane l holds unit l); every wave
// redundantly recomputes the h/c update from the activated-gate LDS arrays
// (identical values -> benign races), which eliminates serial phases and
// needs only 2 barriers per timestep. The h1/c1 update is deferred into the
// next step's phase 1 so its LDS write->read stays wave-local.
__global__ __launch_bounds__(1024, 4)
void lstm_fused_kernel(const float* __restrict__ x,      // [B,T]
                       const float* __restrict__ w_ih0,  // [256,1]
                       const float* __restrict__ w_hh0,  // [256,64]
                       const float* __restrict__ b_ih0,  // [256]
                       const float* __restrict__ b_hh0,  // [256]
                       const float* __restrict__ w_ih1,  // [256,64]
                       const float* __restrict__ w_hh1,  // [256,64]
                       const float* __restrict__ b_ih1,  // [256]
                       const float* __restrict__ b_hh1,  // [256]
                       const float* __restrict__ w1, const float* __restrict__ b1,
                       const float* __restrict__ w2, const float* __restrict__ b2,
                       const float* __restrict__ w3, const float* __restrict__ b3,
                       float* __restrict__ out)          // [B,10]
{
    const int b   = blockIdx.x;
    const int tid = threadIdx.x;
    const int w   = tid >> 6;        // wave 0..15
    const int l   = tid & 63;        // lane
    const int rsub = l & 15;
    const int q   = l >> 4;          // K quarter 0..3
    const int row = w * 16 + rsub;   // gate row 0..255
    const int k0  = q * 16;
    const int gate = w >> 2;         // 0=i 1=f 2=g 3=o (wave-uniform)

    __shared__ __align__(16) float xs[TT];      // 8 KB
    __shared__ __align__(16) float h0s[HH];
    __shared__ __align__(16) float h1s[HH];
    __shared__ __align__(16) float acts0[256];
    __shared__ __align__(16) float acts1[256];
    __shared__ float cls[96];

    // stage x[b][*] coalesced
    {
        const float4* xg = (const float4*)(x + (size_t)b * TT);
        float4* xl = (float4*)xs;
        if (tid < TT / 4) xl[tid] = xg[tid];
    }

    // per-thread weight slices: 3 x 16 floats
    float w0r[16], wAr[16], wBr[16];
    {
        const float4* p0 = (const float4*)(w_hh0 + row * HH + k0);
        const float4* pa = (const float4*)(w_ih1 + row * HH + k0);
        const float4* pb = (const float4*)(w_hh1 + row * HH + k0);
        #pragma unroll
        for (int j = 0; j < 4; ++j) {
            float4 v0 = p0[j], va = pa[j], vb = pb[j];
            w0r[4*j+0]=v0.x; w0r[4*j+1]=v0.y; w0r[4*j+2]=v0.z; w0r[4*j+3]=v0.w;
            wAr[4*j+0]=va.x; wAr[4*j+1]=va.y; wAr[4*j+2]=va.z; wAr[4*j+3]=va.w;
            wBr[4*j+0]=vb.x; wBr[4*j+1]=vb.y; wBr[4*j+2]=vb.z; wBr[4*j+3]=vb.w;
        }
    }
    const float bias0 = b_ih0[row] + b_hh0[row];
    const float bias1 = b_ih1[row] + b_hh1[row];
    const float wih0r = w_ih0[row];

    float c0 = 0.0f, c1 = 0.0f;      // unit l's cell state, replicated per wave
    if (tid < HH) { h0s[tid] = 0.0f; h1s[tid] = 0.0f; }
    if (tid < 256) acts1[tid] = 0.0f;   // makes deferred t=0 update a no-op
    __syncthreads();

    for (int t = 0; t < TT; ++t) {
        // ---- P1a: deferred c1/h1 update (every wave, unit = lane) ----
        {
            float gi = acts1[l], gf = acts1[64 + l], gg = acts1[128 + l], go = acts1[192 + l];
            c1 = fmaf(gf, c1, gi * gg);
            h1s[l] = go * tanh_fast(c1);   // identical values across waves
        }
        // ---- P1b: partial dots over own K-slice ----
        float acc0 = 0.0f, acc1 = 0.0f;
        #pragma unroll
        for (int j = 0; j < 16; j += 4) {
            float4 h4 = *(const float4*)&h0s[k0 + j];
            acc0 = fmaf(w0r[j+0], h4.x, acc0);
            acc0 = fmaf(w0r[j+1], h4.y, acc0);
            acc0 = fmaf(w0r[j+2], h4.z, acc0);
            acc0 = fmaf(w0r[j+3], h4.w, acc0);
        }
        #pragma unroll
        for (int j = 0; j < 16; j += 4) {
            float4 h4 = *(const float4*)&h1s[k0 + j];   // own wave wrote all 64
            acc1 = fmaf(wBr[j+0], h4.x, acc1);
            acc1 = fmaf(wBr[j+1], h4.y, acc1);
            acc1 = fmaf(wBr[j+2], h4.z, acc1);
            acc1 = fmaf(wBr[j+3], h4.w, acc1);
        }
        // combine layer-0 partials across quarters (acc1 combined later)
        acc0 += __shfl_xor(acc0, 16);
        acc0 += __shfl_xor(acc0, 32);
        acc0 += fmaf(wih0r, xs[t], bias0);
        float a0 = (gate == 2) ? tanh_fast(acc0) : sigmoid_fast(acc0);
        if (l < 16) acts0[row] = a0;
        __syncthreads();

        // ---- P2: c0/h0 update (every wave), then layer-1 finish ----
        {
            float gi = acts0[l], gf = acts0[64 + l], gg = acts0[128 + l], go = acts0[192 + l];
            c0 = fmaf(gf, c0, gi * gg);
            h0s[l] = go * tanh_fast(c0);
        }
        #pragma unroll
        for (int j = 0; j < 16; j += 4) {
            float4 h4 = *(const float4*)&h0s[k0 + j];   // own wave wrote all 64
            acc1 = fmaf(wAr[j+0], h4.x, acc1);
            acc1 = fmaf(wAr[j+1], h4.y, acc1);
            acc1 = fmaf(wAr[j+2], h4.z, acc1);
            acc1 = fmaf(wAr[j+3], h4.w, acc1);
        }
        acc1 += __shfl_xor(acc1, 16);
        acc1 += __shfl_xor(acc1, 32);
        acc1 += bias1;
        float a1 = (gate == 2) ? tanh_fast(acc1) : sigmoid_fast(acc1);
        if (l < 16) acts1[row] = a1;
        __syncthreads();
    }

    // final deferred h1 update -> h_last
    if (tid < HH) {
        float gi = acts1[tid], gf = acts1[64 + tid], gg = acts1[128 + tid], go = acts1[192 + tid];
        c1 = fmaf(gf, c1, gi * gg);
        h1s[tid] = go * tanh_fast(c1);
    }
    __syncthreads();

    // ---- classifier head ----
    if (tid < 64) {
        float a = b1[tid];
        #pragma unroll 8
        for (int k = 0; k < 64; ++k) a = fmaf(w1[tid * 64 + k], h1s[k], a);
        cls[tid] = fmaxf(a, 0.0f);
    }
    __syncthreads();
    if (tid < 32) {
        float a = b2[tid];
        #pragma unroll 8
        for (int k = 0; k < 64; ++k) a = fmaf(w2[tid * 64 + k], cls[k], a);
        cls[64 + tid] = fmaxf(a, 0.0f);
    }
    __syncthreads();
    if (tid < 10) {
        float a = b3[tid];
        #pragma unroll 8
        for (int k = 0; k < 32; ++k) a = fmaf(w3[tid * 32 + k], cls[64 + k], a);
        out[b * 10 + tid] = a;
    }
}

extern "C" void kernel_launch(void* const* d_in, const int* in_sizes, int n_in,
                              void* d_out, int out_size, void* d_ws, size_t ws_size,
                              hipStream_t stream) {
    const float* x     = (const float*)d_in[0];
    const float* w_ih0 = (const float*)d_in[1];
    const float* w_hh0 = (const float*)d_in[2];
    const float* b_ih0 = (const float*)d_in[3];
    const float* b_hh0 = (const float*)d_in[4];
    const float* w_ih1 = (const float*)d_in[5];
    const float* w_hh1 = (const float*)d_in[6];
    const float* b_ih1 = (const float*)d_in[7];
    const float* b_hh1 = (const float*)d_in[8];
    const float* w1    = (const float*)d_in[9];
    const float* b1    = (const float*)d_in[10];
    const float* w2    = (const float*)d_in[11];
    const float* b2    = (const float*)d_in[12];
    const float* w3    = (const float*)d_in[13];
    const float* b3    = (const float*)d_in[14];
    float* out = (float*)d_out;

    lstm_fused_kernel<<<BB, 1024, 0, stream>>>(x, w_ih0, w_hh0, b_ih0, b_hh0,
                                               w_ih1, w_hh1, b_ih1, b_hh1,
                                               w1, b1, w2, b2, w3, b3, out);
}

// Round 4
// 4069.080 us; speedup vs baseline: 3.9131x; 1.0059x over previous
//
#include <hip/hip_runtime.h>
#include <math.h>

#define BB 512
#define TT 2048
#define HH 64

__device__ __forceinline__ float sigmoid_fast(float x) {
    float e = __expf(-x);
    return __builtin_amdgcn_rcpf(1.0f + e);
}
__device__ __forceinline__ float tanh_fast(float x) {
    float e = __expf(-2.0f * x);
    return fmaf(2.0f, __builtin_amdgcn_rcpf(1.0f + e), -1.0f);
}

// 1024 threads = 16 waves. wave w owns gate rows [16w, 16w+16); lane quarter
// q owns K-slice [16q, 16q+16). 48 weight floats/thread, PINNED in VGPRs
// (round-3 failure: VGPR_Count=44 -> weights rematerialized as per-step L2
// loads, ~192KB/step/CU of L2 traffic = the 4.1ms bound). waves_per_eu(4,4)
// stops the allocator from chasing 8 waves/EU by shrinking below the 128 cap.
__global__ __launch_bounds__(1024) __attribute__((amdgpu_waves_per_eu(4, 4)))
void lstm_fused_kernel(const float* __restrict__ x,      // [B,T]
                       const float* __restrict__ w_ih0,  // [256,1]
                       const float* __restrict__ w_hh0,  // [256,64]
                       const float* __restrict__ b_ih0,  // [256]
                       const float* __restrict__ b_hh0,  // [256]
                       const float* __restrict__ w_ih1,  // [256,64]
                       const float* __restrict__ w_hh1,  // [256,64]
                       const float* __restrict__ b_ih1,  // [256]
                       const float* __restrict__ b_hh1,  // [256]
                       const float* __restrict__ w1, const float* __restrict__ b1,
                       const float* __restrict__ w2, const float* __restrict__ b2,
                       const float* __restrict__ w3, const float* __restrict__ b3,
                       float* __restrict__ out)          // [B,10]
{
    const int b   = blockIdx.x;
    const int tid = threadIdx.x;
    const int w   = tid >> 6;        // wave 0..15
    const int l   = tid & 63;        // lane
    const int rsub = l & 15;
    const int q   = l >> 4;          // K quarter 0..3
    const int row = w * 16 + rsub;   // gate row 0..255
    const int k0  = q * 16;
    const int gate = w >> 2;         // 0=i 1=f 2=g 3=o (wave-uniform)

    __shared__ __align__(16) float xs[TT];      // 8 KB
    __shared__ __align__(16) float h0s[HH];
    __shared__ __align__(16) float h1s[HH];
    __shared__ __align__(16) float acts0[256];
    __shared__ __align__(16) float acts1[256];
    __shared__ float cls[96];

    // stage x[b][*] coalesced
    {
        const float4* xg = (const float4*)(x + (size_t)b * TT);
        float4* xl = (float4*)xs;
        if (tid < TT / 4) xl[tid] = xg[tid];
    }

    // per-thread weight slices: 3 x 16 floats
    float w0r[16], wAr[16], wBr[16];
    {
        const float4* p0 = (const float4*)(w_hh0 + row * HH + k0);
        const float4* pa = (const float4*)(w_ih1 + row * HH + k0);
        const float4* pb = (const float4*)(w_hh1 + row * HH + k0);
        #pragma unroll
        for (int j = 0; j < 4; ++j) {
            float4 v0 = p0[j], va = pa[j], vb = pb[j];
            w0r[4*j+0]=v0.x; w0r[4*j+1]=v0.y; w0r[4*j+2]=v0.z; w0r[4*j+3]=v0.w;
            wAr[4*j+0]=va.x; wAr[4*j+1]=va.y; wAr[4*j+2]=va.z; wAr[4*j+3]=va.w;
            wBr[4*j+0]=vb.x; wBr[4*j+1]=vb.y; wBr[4*j+2]=vb.z; wBr[4*j+3]=vb.w;
        }
    }
    float bias0 = b_ih0[row] + b_hh0[row];
    float bias1 = b_ih1[row] + b_hh1[row];
    float wih0r = w_ih0[row];

    // ---- PIN weights + per-thread scalars in VGPRs: opaque defs cannot be
    // rematerialized by the scheduler, and live set (~90) fits the 128 cap.
    #pragma unroll
    for (int j = 0; j < 16; ++j) {
        asm volatile("" : "+v"(w0r[j]));
        asm volatile("" : "+v"(wAr[j]));
        asm volatile("" : "+v"(wBr[j]));
    }
    asm volatile("" : "+v"(bias0));
    asm volatile("" : "+v"(bias1));
    asm volatile("" : "+v"(wih0r));

    float c0 = 0.0f, c1 = 0.0f;      // unit l's cell state, replicated per wave
    if (tid < HH) { h0s[tid] = 0.0f; h1s[tid] = 0.0f; }
    if (tid < 256) acts1[tid] = 0.0f;   // makes deferred t=0 update a no-op
    __syncthreads();

    for (int t = 0; t < TT; ++t) {
        // ---- P1a: deferred c1/h1 update (every wave, unit = lane) ----
        {
            float gi = acts1[l], gf = acts1[64 + l], gg = acts1[128 + l], go = acts1[192 + l];
            c1 = fmaf(gf, c1, gi * gg);
            h1s[l] = go * tanh_fast(c1);   // identical values across waves
        }
        // ---- P1b: partial dots over own K-slice ----
        float acc0 = 0.0f, acc1 = 0.0f;
        #pragma unroll
        for (int j = 0; j < 16; j += 4) {
            float4 h4 = *(const float4*)&h0s[k0 + j];
            acc0 = fmaf(w0r[j+0], h4.x, acc0);
            acc0 = fmaf(w0r[j+1], h4.y, acc0);
            acc0 = fmaf(w0r[j+2], h4.z, acc0);
            acc0 = fmaf(w0r[j+3], h4.w, acc0);
        }
        #pragma unroll
        for (int j = 0; j < 16; j += 4) {
            float4 h4 = *(const float4*)&h1s[k0 + j];   // own wave wrote all 64
            acc1 = fmaf(wBr[j+0], h4.x, acc1);
            acc1 = fmaf(wBr[j+1], h4.y, acc1);
            acc1 = fmaf(wBr[j+2], h4.z, acc1);
            acc1 = fmaf(wBr[j+3], h4.w, acc1);
        }
        // combine layer-0 partials across quarters (acc1 combined later)
        acc0 += __shfl_xor(acc0, 16);
        acc0 += __shfl_xor(acc0, 32);
        acc0 += fmaf(wih0r, xs[t], bias0);
        float a0 = (gate == 2) ? tanh_fast(acc0) : sigmoid_fast(acc0);
        if (l < 16) acts0[row] = a0;
        __syncthreads();

        // ---- P2: c0/h0 update (every wave), then layer-1 finish ----
        {
            float gi = acts0[l], gf = acts0[64 + l], gg = acts0[128 + l], go = acts0[192 + l];
            c0 = fmaf(gf, c0, gi * gg);
            h0s[l] = go * tanh_fast(c0);
        }
        #pragma unroll
        for (int j = 0; j < 16; j += 4) {
            float4 h4 = *(const float4*)&h0s[k0 + j];   // own wave wrote all 64
            acc1 = fmaf(wAr[j+0], h4.x, acc1);
            acc1 = fmaf(wAr[j+1], h4.y, acc1);
            acc1 = fmaf(wAr[j+2], h4.z, acc1);
            acc1 = fmaf(wAr[j+3], h4.w, acc1);
        }
        acc1 += __shfl_xor(acc1, 16);
        acc1 += __shfl_xor(acc1, 32);
        acc1 += bias1;
        float a1 = (gate == 2) ? tanh_fast(acc1) : sigmoid_fast(acc1);
        if (l < 16) acts1[row] = a1;
        __syncthreads();
    }

    // final deferred h1 update -> h_last
    if (tid < HH) {
        float gi = acts1[tid], gf = acts1[64 + tid], gg = acts1[128 + tid], go = acts1[192 + tid];
        c1 = fmaf(gf, c1, gi * gg);
        h1s[tid] = go * tanh_fast(c1);
    }
    __syncthreads();

    // ---- classifier head ----
    if (tid < 64) {
        float a = b1[tid];
        #pragma unroll 8
        for (int k = 0; k < 64; ++k) a = fmaf(w1[tid * 64 + k], h1s[k], a);
        cls[tid] = fmaxf(a, 0.0f);
    }
    __syncthreads();
    if (tid < 32) {
        float a = b2[tid];
        #pragma unroll 8
        for (int k = 0; k < 64; ++k) a = fmaf(w2[tid * 64 + k], cls[k], a);
        cls[64 + tid] = fmaxf(a, 0.0f);
    }
    __syncthreads();
    if (tid < 10) {
        float a = b3[tid];
        #pragma unroll 8
        for (int k = 0; k < 32; ++k) a = fmaf(w3[tid * 32 + k], cls[64 + k], a);
        out[b * 10 + tid] = a;
    }
}

extern "C" void kernel_launch(void* const* d_in, const int* in_sizes, int n_in,
                              void* d_out, int out_size, void* d_ws, size_t ws_size,
                              hipStream_t stream) {
    const float* x     = (const float*)d_in[0];
    const float* w_ih0 = (const float*)d_in[1];
    const float* w_hh0 = (const float*)d_in[2];
    const float* b_ih0 = (const float*)d_in[3];
    const float* b_hh0 = (const float*)d_in[4];
    const float* w_ih1 = (const float*)d_in[5];
    const float* w_hh1 = (const float*)d_in[6];
    const float* b_ih1 = (const float*)d_in[7];
    const float* b_hh1 = (const float*)d_in[8];
    const float* w1    = (const float*)d_in[9];
    const float* b1    = (const float*)d_in[10];
    const float* w2    = (const float*)d_in[11];
    const float* b2    = (const float*)d_in[12];
    const float* w3    = (const float*)d_in[13];
    const float* b3    = (const float*)d_in[14];
    float* out = (float*)d_out;

    lstm_fused_kernel<<<BB, 1024, 0, stream>>>(x, w_ih0, w_hh0, b_ih0, b_hh0,
                                               w_ih1, w_hh1, b_ih1, b_hh1,
                                               w1, b1, w2, b2, w3, b3, out);
}